// Round 4
// baseline (65.729 us; speedup 1.0000x reference)
//
#include <hip/hip_runtime.h>

// SO3 encode: z[B, 96] -> (mean[B,16,3,3], logvar[B,16,3])
// mean = I + s1*A + s2*A^2 (Rodrigues), logvar = 5.4*sigmoid(logits) - 9.2
//
// One thread computes 4 gaussians of one row (all loads aligned float4).
// The store-coalescing transpose goes through *wave-private* LDS regions:
// lane data is only ever read back by the same wave, so a same-wave
// s_waitcnt lgkmcnt(0) replaces __syncthreads() -- no s_barrier, no
// vmcnt(0) drain, every wave streams independently. Output stores are
// nontemporal (write-once stream).
//
// NOTE: __builtin_nontemporal_load/store require native clang vector types,
// not HIP_vector_type -- use ext_vector_type(4) float throughout.

#define BLOCK 256

typedef float f4 __attribute__((ext_vector_type(4)));

__global__ __launch_bounds__(BLOCK) void so3_encode_kernel(
    const float* __restrict__ z,
    float* __restrict__ out_mean,
    float* __restrict__ out_logvar)
{
    __shared__ float lds_m[BLOCK * 36];   // 36 KB, per-wave 9216 B regions
    __shared__ float lds_l[BLOCK * 12];   // 12 KB, per-wave 3072 B regions

    const int t    = threadIdx.x;
    const int lane = t & 63;
    const int wave = t >> 6;
    const int idx  = blockIdx.x * BLOCK + t;   // grid exact: B*4 % 256 == 0
    const int b    = idx >> 2;   // batch row
    const int k    = idx & 3;    // quad of 4 gaussians (of 16)

    // axis params: z[b, k*12 .. k*12+11]  (byte offset b*384 + k*48, 16B aligned)
    const f4* za = reinterpret_cast<const f4*>(z + (size_t)b * 96 + k * 12);
    f4 a0 = __builtin_nontemporal_load(za + 0);
    f4 a1 = __builtin_nontemporal_load(za + 1);
    f4 a2 = __builtin_nontemporal_load(za + 2);
    // logvar logits: z[b, 48 + k*12 .. ]
    const f4* zl = reinterpret_cast<const f4*>(z + (size_t)b * 96 + 48 + k * 12);
    f4 l0 = __builtin_nontemporal_load(zl + 0);
    f4 l1 = __builtin_nontemporal_load(zl + 1);
    f4 l2 = __builtin_nontemporal_load(zl + 2);

    float av[12] = {a0.x, a0.y, a0.z, a0.w,
                    a1.x, a1.y, a1.z, a1.w,
                    a2.x, a2.y, a2.z, a2.w};
    float lv[12] = {l0.x, l0.y, l0.z, l0.w,
                    l1.x, l1.y, l1.z, l1.w,
                    l2.x, l2.y, l2.z, l2.w};

    float m[36];
    #pragma unroll
    for (int j = 0; j < 4; ++j) {
        float a  = av[3 * j + 0];
        float bb = av[3 * j + 1];
        float c  = av[3 * j + 2];
        float th2 = a * a + bb * bb + c * c;
        bool small = th2 < 1e-8f;
        float t2 = small ? 1.0f : th2;       // safe denom, matches reference
        float tt = sqrtf(t2);
        float sn, cs;
        __sincosf(tt, &sn, &cs);
        float inv_t2 = 1.0f / t2;
        float s1 = small ? (1.0f - th2 * (1.0f / 6.0f))  : (sn * tt * inv_t2);     // sin(t)/t
        float s2 = small ? (0.5f - th2 * (1.0f / 24.0f)) : ((1.0f - cs) * inv_t2); // (1-cos t)/t^2

        float* o = m + 9 * j;
        float ab = a * bb, ac = a * c, bc = bb * c;
        o[0] = 1.0f - s2 * (a * a + bb * bb);
        o[1] = s1 * a  - s2 * bc;
        o[2] = s1 * bb + s2 * ac;
        o[3] = -s1 * a - s2 * bc;
        o[4] = 1.0f - s2 * (a * a + c * c);
        o[5] = s1 * c  - s2 * ab;
        o[6] = -s1 * bb + s2 * ac;
        o[7] = -s1 * c  - s2 * ab;
        o[8] = 1.0f - s2 * (bb * bb + c * c);
    }

    float lg[12];
    #pragma unroll
    for (int j = 0; j < 12; ++j) {
        lg[j] = 5.4f / (1.0f + __expf(-lv[j])) - 9.2f;
    }

    // ---- stage into this wave's private LDS regions
    //      (stride 36 floats: start banks 4l%32, 16B/bank/cycle even spread ->
    //       conflict-free minimum; same for stride 12)
    f4* lm = reinterpret_cast<f4*>(lds_m + wave * (64 * 36) + lane * 36);
    #pragma unroll
    for (int q = 0; q < 9; ++q) {
        f4 v = {m[4 * q + 0], m[4 * q + 1], m[4 * q + 2], m[4 * q + 3]};
        lm[q] = v;
    }

    f4* ll = reinterpret_cast<f4*>(lds_l + wave * (64 * 12) + lane * 12);
    #pragma unroll
    for (int q = 0; q < 3; ++q) {
        f4 v = {lg[4 * q + 0], lg[4 * q + 1], lg[4 * q + 2], lg[4 * q + 3]};
        ll[q] = v;
    }

    // ---- same-wave write->read fence: all exchange is wave-local, so a
    //      lgkmcnt(0) wait (not __syncthreads/s_barrier) is sufficient.
    asm volatile("s_waitcnt lgkmcnt(0)" ::: "memory");
    __builtin_amdgcn_sched_barrier(0);

    // ---- coalesced nontemporal writeout: lane l stores byte offset l*16,
    //      contiguous 1 KB per wave-instruction
    const f4* lmw = reinterpret_cast<const f4*>(lds_m + wave * (64 * 36));
    f4* om = reinterpret_cast<f4*>(out_mean)
           + (size_t)blockIdx.x * (BLOCK * 9) + wave * (64 * 9);
    #pragma unroll
    for (int i = 0; i < 9; ++i)
        __builtin_nontemporal_store(lmw[i * 64 + lane], om + i * 64 + lane);

    const f4* llw = reinterpret_cast<const f4*>(lds_l + wave * (64 * 12));
    f4* ol = reinterpret_cast<f4*>(out_logvar)
           + (size_t)blockIdx.x * (BLOCK * 3) + wave * (64 * 3);
    #pragma unroll
    for (int i = 0; i < 3; ++i)
        __builtin_nontemporal_store(llw[i * 64 + lane], ol + i * 64 + lane);
}

extern "C" void kernel_launch(void* const* d_in, const int* in_sizes, int n_in,
                              void* d_out, int out_size, void* d_ws, size_t ws_size,
                              hipStream_t stream) {
    const float* z = (const float*)d_in[0];
    const int B = in_sizes[0] / 96;          // 6 * N_GAUSS = 96 floats per row
    float* out_mean = (float*)d_out;                              // B*16*9 floats
    float* out_logvar = (float*)d_out + (size_t)B * 16 * 9;       // B*16*3 floats

    const int nthreads = B * 4;              // one thread per 4 gaussians
    const int grid = nthreads / BLOCK;       // 1,048,576 / 256 = 4096 blocks (exact)
    so3_encode_kernel<<<grid, BLOCK, 0, stream>>>(z, out_mean, out_logvar);
}

// Round 5
// 54.016 us; speedup vs baseline: 1.2168x; 1.2168x over previous
//
#include <hip/hip_runtime.h>

// SO3 encode: z[B, 96] -> (mean[B,16,3,3], logvar[B,16,3])
// mean = I + s1*A + s2*A^2 (Rodrigues), logvar = 5.4*sigmoid(logits) - 9.2
//
// One thread computes 4 gaussians of one row (all loads aligned float4).
// Store-coalescing transpose via *wave-private* LDS regions: lane data is
// only ever read back by the same wave, so a same-wave s_waitcnt lgkmcnt(0)
// replaces __syncthreads() -- no s_barrier, waves stream independently.
//
// R4 post-mortem: nontemporal hints regressed 53.8->65.7us (NT defeats L2
// write aggregation). This revision removes ALL NT hints (single change).

#define BLOCK 256

typedef float f4 __attribute__((ext_vector_type(4)));

__global__ __launch_bounds__(BLOCK) void so3_encode_kernel(
    const float* __restrict__ z,
    float* __restrict__ out_mean,
    float* __restrict__ out_logvar)
{
    __shared__ float lds_m[BLOCK * 36];   // 36 KB, per-wave 9216 B regions
    __shared__ float lds_l[BLOCK * 12];   // 12 KB, per-wave 3072 B regions

    const int t    = threadIdx.x;
    const int lane = t & 63;
    const int wave = t >> 6;
    const int idx  = blockIdx.x * BLOCK + t;   // grid exact: B*4 % 256 == 0
    const int b    = idx >> 2;   // batch row
    const int k    = idx & 3;    // quad of 4 gaussians (of 16)

    // axis params: z[b, k*12 .. k*12+11]  (byte offset b*384 + k*48, 16B aligned)
    const f4* za = reinterpret_cast<const f4*>(z + (size_t)b * 96 + k * 12);
    f4 a0 = za[0];
    f4 a1 = za[1];
    f4 a2 = za[2];
    // logvar logits: z[b, 48 + k*12 .. ]
    const f4* zl = reinterpret_cast<const f4*>(z + (size_t)b * 96 + 48 + k * 12);
    f4 l0 = zl[0];
    f4 l1 = zl[1];
    f4 l2 = zl[2];

    float av[12] = {a0.x, a0.y, a0.z, a0.w,
                    a1.x, a1.y, a1.z, a1.w,
                    a2.x, a2.y, a2.z, a2.w};
    float lv[12] = {l0.x, l0.y, l0.z, l0.w,
                    l1.x, l1.y, l1.z, l1.w,
                    l2.x, l2.y, l2.z, l2.w};

    float m[36];
    #pragma unroll
    for (int j = 0; j < 4; ++j) {
        float a  = av[3 * j + 0];
        float bb = av[3 * j + 1];
        float c  = av[3 * j + 2];
        float th2 = a * a + bb * bb + c * c;
        bool small = th2 < 1e-8f;
        float t2 = small ? 1.0f : th2;       // safe denom, matches reference
        float tt = sqrtf(t2);
        float sn, cs;
        __sincosf(tt, &sn, &cs);
        float inv_t2 = 1.0f / t2;
        float s1 = small ? (1.0f - th2 * (1.0f / 6.0f))  : (sn * tt * inv_t2);     // sin(t)/t
        float s2 = small ? (0.5f - th2 * (1.0f / 24.0f)) : ((1.0f - cs) * inv_t2); // (1-cos t)/t^2

        float* o = m + 9 * j;
        float ab = a * bb, ac = a * c, bc = bb * c;
        o[0] = 1.0f - s2 * (a * a + bb * bb);
        o[1] = s1 * a  - s2 * bc;
        o[2] = s1 * bb + s2 * ac;
        o[3] = -s1 * a - s2 * bc;
        o[4] = 1.0f - s2 * (a * a + c * c);
        o[5] = s1 * c  - s2 * ab;
        o[6] = -s1 * bb + s2 * ac;
        o[7] = -s1 * c  - s2 * ab;
        o[8] = 1.0f - s2 * (bb * bb + c * c);
    }

    float lg[12];
    #pragma unroll
    for (int j = 0; j < 12; ++j) {
        lg[j] = 5.4f / (1.0f + __expf(-lv[j])) - 9.2f;
    }

    // ---- stage into this wave's private LDS regions
    //      (stride 36 floats: start banks 4l%32, 16B/bank even spread ->
    //       conflict-free minimum; same for stride 12)
    f4* lm = reinterpret_cast<f4*>(lds_m + wave * (64 * 36) + lane * 36);
    #pragma unroll
    for (int q = 0; q < 9; ++q) {
        f4 v = {m[4 * q + 0], m[4 * q + 1], m[4 * q + 2], m[4 * q + 3]};
        lm[q] = v;
    }

    f4* ll = reinterpret_cast<f4*>(lds_l + wave * (64 * 12) + lane * 12);
    #pragma unroll
    for (int q = 0; q < 3; ++q) {
        f4 v = {lg[4 * q + 0], lg[4 * q + 1], lg[4 * q + 2], lg[4 * q + 3]};
        ll[q] = v;
    }

    // ---- same-wave write->read fence: all exchange is wave-local, so a
    //      lgkmcnt(0) wait (not __syncthreads/s_barrier) is sufficient.
    asm volatile("s_waitcnt lgkmcnt(0)" ::: "memory");
    __builtin_amdgcn_sched_barrier(0);

    // ---- coalesced writeout: lane l stores byte offset l*16,
    //      contiguous 1 KB per wave-instruction
    const f4* lmw = reinterpret_cast<const f4*>(lds_m + wave * (64 * 36));
    f4* om = reinterpret_cast<f4*>(out_mean)
           + (size_t)blockIdx.x * (BLOCK * 9) + wave * (64 * 9);
    #pragma unroll
    for (int i = 0; i < 9; ++i)
        om[i * 64 + lane] = lmw[i * 64 + lane];

    const f4* llw = reinterpret_cast<const f4*>(lds_l + wave * (64 * 12));
    f4* ol = reinterpret_cast<f4*>(out_logvar)
           + (size_t)blockIdx.x * (BLOCK * 3) + wave * (64 * 3);
    #pragma unroll
    for (int i = 0; i < 3; ++i)
        ol[i * 64 + lane] = llw[i * 64 + lane];
}

extern "C" void kernel_launch(void* const* d_in, const int* in_sizes, int n_in,
                              void* d_out, int out_size, void* d_ws, size_t ws_size,
                              hipStream_t stream) {
    const float* z = (const float*)d_in[0];
    const int B = in_sizes[0] / 96;          // 6 * N_GAUSS = 96 floats per row
    float* out_mean = (float*)d_out;                              // B*16*9 floats
    float* out_logvar = (float*)d_out + (size_t)B * 16 * 9;       // B*16*3 floats

    const int nthreads = B * 4;              // one thread per 4 gaussians
    const int grid = nthreads / BLOCK;       // 1,048,576 / 256 = 4096 blocks (exact)
    so3_encode_kernel<<<grid, BLOCK, 0, stream>>>(z, out_mean, out_logvar);
}

// Round 6
// 51.662 us; speedup vs baseline: 1.2723x; 1.0456x over previous
//
#include <hip/hip_runtime.h>

// SO3 encode: z[B, 96] -> (mean[B,16,3,3], logvar[B,16,3])
// mean = I + s1*A + s2*A^2 (Rodrigues), logvar = 5.4*sigmoid(logits) - 9.2
//
// R6: one gaussian per thread (was 4). LDS transpose staging drops from
// 48 KB/block to 12 KB/block -> occupancy cap moves from 12 waves/CU to the
// 32-waves/CU hardware limit, for better load-latency hiding (R5 post-mortem:
// barrier was free, NT hurt; residual 15% gap vs mixed-stream ceiling is
// latency hiding at 3 waves/SIMD).
//   - input: consecutive lanes own consecutive 12-B chunks -> coalesced
//   - LDS mean writes: stride 9 floats, gcd(9,32)=1 -> conflict-free
//   - LDS logvar writes: stride 3, gcd(3,32)=1 -> conflict-free
//   - readout: linear float4, contiguous 1 KB per wave-store instruction
//   - all exchange wave-local -> s_waitcnt lgkmcnt(0), no s_barrier

#define BLOCK 256

typedef float f4 __attribute__((ext_vector_type(4)));

__global__ __launch_bounds__(BLOCK, 8) void so3_encode_kernel(
    const float* __restrict__ z,
    float* __restrict__ out_mean,
    float* __restrict__ out_logvar)
{
    __shared__ float smean[4][64 * 9];   // per-wave 2304 B, total 9 KB
    __shared__ float slv[4][64 * 3];     // per-wave  768 B, total 3 KB

    const int t    = threadIdx.x;
    const int lane = t & 63;
    const int w    = t >> 6;
    const int g    = blockIdx.x * BLOCK + t;   // gaussian index, grid exact
    const int b    = g >> 4;                   // batch row
    const int s    = g & 15;                   // gaussian slot in row

    // axis params z[b, s*3 .. s*3+2], logits z[b, 48 + s*3 .. ]
    const float* zr = z + (size_t)b * 96 + s * 3;
    float a  = zr[0];
    float bb = zr[1];
    float c  = zr[2];
    float x0 = zr[48];
    float x1 = zr[49];
    float x2 = zr[50];

    // ---- Rodrigues
    float th2 = a * a + bb * bb + c * c;
    bool small = th2 < 1e-8f;
    float t2 = small ? 1.0f : th2;        // safe denom, matches reference
    float tt = sqrtf(t2);
    float sn, cs;
    __sincosf(tt, &sn, &cs);
    float inv_t2 = 1.0f / t2;
    float s1 = small ? (1.0f - th2 * (1.0f / 6.0f))  : (sn * tt * inv_t2);     // sin(t)/t
    float s2 = small ? (0.5f - th2 * (1.0f / 24.0f)) : ((1.0f - cs) * inv_t2); // (1-cos t)/t^2

    float ab = a * bb, ac = a * c, bc = bb * c;
    float* sm = &smean[w][lane * 9];
    sm[0] = 1.0f - s2 * (a * a + bb * bb);
    sm[1] = s1 * a  - s2 * bc;
    sm[2] = s1 * bb + s2 * ac;
    sm[3] = -s1 * a - s2 * bc;
    sm[4] = 1.0f - s2 * (a * a + c * c);
    sm[5] = s1 * c  - s2 * ab;
    sm[6] = -s1 * bb + s2 * ac;
    sm[7] = -s1 * c  - s2 * ab;
    sm[8] = 1.0f - s2 * (bb * bb + c * c);

    float* sl = &slv[w][lane * 3];
    sl[0] = 5.4f / (1.0f + __expf(-x0)) - 9.2f;
    sl[1] = 5.4f / (1.0f + __expf(-x1)) - 9.2f;
    sl[2] = 5.4f / (1.0f + __expf(-x2)) - 9.2f;

    // ---- same-wave write->read fence (exchange is wave-local only)
    asm volatile("s_waitcnt lgkmcnt(0)" ::: "memory");
    __builtin_amdgcn_sched_barrier(0);

    // ---- coalesced writeout
    const int g_base = blockIdx.x * BLOCK + (w << 6);

    const f4* smv = reinterpret_cast<const f4*>(&smean[w][0]);   // 144 f4
    f4* om = reinterpret_cast<f4*>(out_mean + (size_t)g_base * 9);
    om[lane]      = smv[lane];
    om[64 + lane] = smv[64 + lane];
    if (lane < 16) om[128 + lane] = smv[128 + lane];

    const f4* slvv = reinterpret_cast<const f4*>(&slv[w][0]);    // 48 f4
    f4* ol = reinterpret_cast<f4*>(out_logvar + (size_t)g_base * 3);
    if (lane < 48) ol[lane] = slvv[lane];
}

extern "C" void kernel_launch(void* const* d_in, const int* in_sizes, int n_in,
                              void* d_out, int out_size, void* d_ws, size_t ws_size,
                              hipStream_t stream) {
    const float* z = (const float*)d_in[0];
    const int B = in_sizes[0] / 96;          // 6 * N_GAUSS = 96 floats per row
    float* out_mean = (float*)d_out;                              // B*16*9 floats
    float* out_logvar = (float*)d_out + (size_t)B * 16 * 9;       // B*16*3 floats

    const int nthreads = B * 16;             // one thread per gaussian
    const int grid = nthreads / BLOCK;       // 4,194,304 / 256 = 16384 blocks
    so3_encode_kernel<<<grid, BLOCK, 0, stream>>>(z, out_mean, out_logvar);
}